// Round 17
// baseline (244.022 us; speedup 1.0000x reference)
//
#include <hip/hip_runtime.h>

#define B_ 2
#define S_ 2048
#define E_ 1024
#define H_ 16
#define D_ 64

typedef __bf16 bf16_t;
typedef __bf16 bf16x8 __attribute__((ext_vector_type(8)));
typedef __bf16 bf16x4 __attribute__((ext_vector_type(4)));
typedef float f32x4 __attribute__((ext_vector_type(4)));

// ws layout (bf16 element offsets)
#define OFF_XB   0u
#define OFF_WB   12582912u
#define OFF_QH   16777216u
#define OFF_CTX  29360128u
#define XSZ      4194304u
#define WSZ      1048576u

__device__ __forceinline__ f32x4 mfma16(bf16x8 a, bf16x8 b, f32x4 c) {
  return __builtin_amdgcn_mfma_f32_16x16x32_bf16(a, b, c, 0, 0, 0);
}

__device__ __forceinline__ void gl_lds16(const bf16_t* g, bf16_t* l) {
  __builtin_amdgcn_global_load_lds(
      (const __attribute__((address_space(1))) void*)g,
      (__attribute__((address_space(3))) void*)l, 16, 0, 0);
}

// ---------------------------------------------------------------------------
// Kernel 0: fp32 -> bf16 convert into ws.
// ---------------------------------------------------------------------------
__global__ __launch_bounds__(256) void convert_kernel(
    const float* __restrict__ q, const float* __restrict__ k, const float* __restrict__ v,
    const float* __restrict__ wq, const float* __restrict__ wk,
    const float* __restrict__ wv, const float* __restrict__ wo,
    bf16_t* __restrict__ ws)
{
  const int z = blockIdx.z;
  const float* src;
  bf16_t* dst;
  int n;
  if (z < 3) {
    src = (z == 0) ? q : (z == 1) ? k : v;
    dst = ws + (size_t)z * XSZ;
    n = XSZ;
  } else {
    src = (z == 3) ? wq : (z == 4) ? wk : (z == 5) ? wv : wo;
    dst = ws + OFF_WB + (size_t)(z - 3) * WSZ;
    n = WSZ;
  }
  const int stride = 512 * 256 * 8;
  for (int base = (int)(blockIdx.x * 256 + threadIdx.x) * 8; base < n; base += stride) {
    float4 a = *(const float4*)(src + base);
    float4 b = *(const float4*)(src + base + 4);
    bf16x8 o = { (bf16_t)a.x, (bf16_t)a.y, (bf16_t)a.z, (bf16_t)a.w,
                 (bf16_t)b.x, (bf16_t)b.y, (bf16_t)b.z, (bf16_t)b.w };
    *(bf16x8*)(dst + base) = o;
  }
}

// ---------------------------------------------------------------------------
// Kernel 1: QKV projection, m97 structure.
// ---------------------------------------------------------------------------
__global__ __launch_bounds__(256) void qkv_gemm_kernel(
    bf16_t* __restrict__ wsb,
    const float* __restrict__ bq, const float* __restrict__ bk, const float* __restrict__ bv)
{
  __shared__ __align__(16) bf16_t sA[128 * 64];
  __shared__ __align__(16) bf16_t sB[128 * 64];

  const int z = blockIdx.z;
  const bf16_t* A  = wsb + (size_t)z * XSZ;
  const bf16_t* Bm = wsb + OFF_WB + (size_t)z * WSZ;
  const float* bias = (z == 0) ? bq : (z == 1) ? bk : bv;
  bf16_t* out = wsb + OFF_QH + (size_t)z * XSZ;

  const int t = threadIdx.x, lane = t & 63, w = t >> 6;
  const int wm = (w >> 1) << 6, wn = (w & 1) << 6;
  const int m0 = blockIdx.x << 7, n0 = blockIdx.y << 7;
  const int l15 = lane & 15, lg = lane >> 4;

  const int r0 = w << 5;
  const int grow = r0 + (lane >> 3);
  const int gcol = (lane & 7) << 3;
  const bf16_t* gA = A + ((size_t)(m0 + grow) << 10) + gcol;
  const bf16_t* gB = Bm + ((size_t)(n0 + grow) << 10) + gcol;
  bf16_t* lA = sA + (r0 << 6);
  bf16_t* lB = sB + (r0 << 6);

  f32x4 acc[4][4] = {};

  for (int k0 = 0; k0 < E_; k0 += 64) {
    __syncthreads();
#pragma unroll
    for (int i = 0; i < 4; ++i) {
      gl_lds16(gA + k0 + ((size_t)(i << 3) << 10), lA + (i << 9));
      gl_lds16(gB + k0 + ((size_t)(i << 3) << 10), lB + (i << 9));
    }
    __syncthreads();
#pragma unroll
    for (int kk = 0; kk < 2; ++kk) {
      bf16x8 af[4], bfr[4];
#pragma unroll
      for (int i = 0; i < 4; ++i)
        af[i] = *(const bf16x8*)(sA + ((wm + (i << 4) + l15) << 6) + (kk << 5) + (lg << 3));
#pragma unroll
      for (int j = 0; j < 4; ++j)
        bfr[j] = *(const bf16x8*)(sB + ((wn + (j << 4) + l15) << 6) + (kk << 5) + (lg << 3));
#pragma unroll
      for (int i = 0; i < 4; ++i)
#pragma unroll
        for (int j = 0; j < 4; ++j)
          acc[i][j] = mfma16(af[i], bfr[j], acc[i][j]);
    }
  }

#pragma unroll
  for (int j = 0; j < 4; ++j) {
    const int n = n0 + wn + (j << 4) + l15;
    const float bn = bias[n];
    const int h = n >> 6, d = n & 63;
#pragma unroll
    for (int i = 0; i < 4; ++i) {
#pragma unroll
      for (int r = 0; r < 4; ++r) {
        const int m = m0 + wm + (i << 4) + (lg << 2) + r;
        const int b = m >> 11, s = m & (S_ - 1);
        out[(((size_t)(b * H_ + h)) * S_ + s) * D_ + d] = (bf16_t)(acc[i][j][r] + bn);
      }
    }
  }
}

// ---------------------------------------------------------------------------
// Kernel 2: fused causal attention, restructured phases:
//  Pass 1: sums-only (K-stage + QK^T + exp-sums) — light, no V/PV/plds.
//  Pass 2: single P materialization: QK^T -> normalized P(bf16) -> plds;
//          PV consumes plds; coop full-line store (bf16->f32) from plds.
//          Stores of tile kt drain under tile kt+1's staging + 16 MFMA.
//  Fill at end (R14 form).  XCD remap + in-place swizzled V transpose kept.
// ---------------------------------------------------------------------------
__global__ __launch_bounds__(256, 6) void attn_kernel(
    const bf16_t* __restrict__ qh, const bf16_t* __restrict__ kh, const bf16_t* __restrict__ vh,
    float* __restrict__ attn, bf16_t* __restrict__ ctx)
{
  constexpr int STR = 72;
  __shared__ __align__(16) char smem[26624];
  bf16_t* klds  = (bf16_t*)smem;                 // [64][72]
  bf16_t* vbuf  = (bf16_t*)(smem + 9216);        // [64][64] V rows -> V^T swz
  bf16_t* plds_ = (bf16_t*)(smem + 17408);       // 4 x [16][72] normalized P

  // --- XCD-aware remap: XCD(d)=d%8 owns bh in {4*xcd .. 4*xcd+3} ---
  const int d_  = blockIdx.x;          // 0..1023
  const int xcd = d_ & 7;
  const int bh  = (xcd << 2) + ((d_ >> 3) & 3);
  const int qt  = d_ >> 5;             // 0..31

  const int t    = threadIdx.x;
  const int lane = t & 63;
  const int w    = t >> 6;
  const int l15  = lane & 15;
  const int lg   = lane >> 4;
  const int q0 = qt << 6;
  const size_t hbase = (size_t)bh * (size_t)(S_ * D_);

  const int qr_lane = q0 + (w << 4) + l15;
  const bf16_t* qp = qh + hbase + (size_t)qr_lane * D_ + (lg << 3);
  const bf16x8 q_lo = *(const bf16x8*)qp;
  const bf16x8 q_hi = *(const bf16x8*)(qp + 32);

  constexpr float SC = 0.18033688f;  // log2(e)/8

  const int td  = t & 63;
  const int tk0 = (t >> 6) << 3;     // 0,8,16,24 (col octet per wave)
  const int sr = t >> 3;
  const int sc = (t & 7) << 3;
  const int vtw0 = td * 64 + (tk0 ^ ((td & 7) << 3));
  const int vtw1 = td * 64 + ((tk0 + 32) ^ ((td & 7) << 3));

  // ---- pass 1: row exp-sums only ----
  float s_sum = 0.f;
  for (int kt = 0; kt <= qt; ++kt) {
    __syncthreads();
    {
      const bf16_t* kb = kh + hbase + (size_t)((kt << 6) + sr) * D_ + sc;
      *(bf16x8*)(klds + sr * STR + sc) = *(const bf16x8*)kb;
      *(bf16x8*)(klds + (sr + 32) * STR + sc) = *(const bf16x8*)(kb + 32 * D_);
    }
    __syncthreads();
#pragma unroll
    for (int j = 0; j < 4; ++j) {
      const bf16_t* kp = klds + ((j << 4) + l15) * STR + (lg << 3);
      bf16x8 k_lo = *(const bf16x8*)kp;
      bf16x8 k_hi = *(const bf16x8*)(kp + 32);
      f32x4 sf = { 0.f, 0.f, 0.f, 0.f };
      sf = mfma16(k_lo, q_lo, sf);
      sf = mfma16(k_hi, q_hi, sf);
      const int kc = (kt << 6) + (j << 4) + (lg << 2);
      const int lim = qr_lane - kc;
#pragma unroll
      for (int r = 0; r < 4; ++r)
        s_sum += (r <= lim) ? exp2f(sf[r] * SC) : 0.f;
    }
  }
  float s = s_sum;
  s += __shfl_xor(s, 16);
  s += __shfl_xor(s, 32);
  const float inv_s = 1.f / s;       // own row qr_lane, every lane

  // ---- pass 2: P once (normalized) -> plds; PV; coop store from plds ----
  f32x4 oacc[4] = {};
  float* attn_bh = attn + (size_t)bh * (size_t)(S_ * S_);
  const int frow = t >> 4;           // 0..15
  const int fcol = (t & 15) << 2;    // 0..60

  for (int kt = 0; kt <= qt; ++kt) {
    __syncthreads();   // prev tile: PV vbuf reads + coop plds reads done
    {
      const bf16_t* kb = kh + hbase + (size_t)((kt << 6) + sr) * D_ + sc;
      const bf16_t* vb = vh + hbase + (size_t)((kt << 6) + sr) * D_ + sc;
      *(bf16x8*)(klds + sr * STR + sc) = *(const bf16x8*)kb;
      *(bf16x8*)(klds + (sr + 32) * STR + sc) = *(const bf16x8*)(kb + 32 * D_);
      *(bf16x8*)(vbuf + (sr << 6) + sc) = *(const bf16x8*)vb;
      *(bf16x8*)(vbuf + ((sr + 32) << 6) + sc) = *(const bf16x8*)(vb + 32 * D_);
    }
    __syncthreads();   // staging visible
    // transpose-read V columns into registers
    bf16x8 col0, col1;
#pragma unroll
    for (int e = 0; e < 8; ++e) col0[e] = vbuf[((tk0 + e) << 6) + td];
#pragma unroll
    for (int e = 0; e < 8; ++e) col1[e] = vbuf[((tk0 + 32 + e) << 6) + td];
    // swapped QK^T -> normalized P (bf16) -> plds
#pragma unroll
    for (int j = 0; j < 4; ++j) {
      const bf16_t* kp = klds + ((j << 4) + l15) * STR + (lg << 3);
      bf16x8 k_lo = *(const bf16x8*)kp;
      bf16x8 k_hi = *(const bf16x8*)(kp + 32);
      f32x4 sf = { 0.f, 0.f, 0.f, 0.f };
      sf = mfma16(k_lo, q_lo, sf);
      sf = mfma16(k_hi, q_hi, sf);
      const int kc = (kt << 6) + (j << 4) + (lg << 2);
      const int lim = qr_lane - kc;
      bf16x4 pb;
#pragma unroll
      for (int r = 0; r < 4; ++r)
        pb[r] = (bf16_t)((r <= lim) ? exp2f(sf[r] * SC) * inv_s : 0.f);
      *(bf16x4*)(plds_ + w * 1152 + l15 * STR + (j << 4) + (lg << 2)) = pb;
    }
    __syncthreads();   // transpose reads done + plds complete (all waves)
    // write V^T (swizzled) back into vbuf
    *(bf16x8*)(vbuf + vtw0) = col0;
    *(bf16x8*)(vbuf + vtw1) = col1;
    __syncthreads();   // V^T visible
    // PV: pa from plds (wave-private rows), vb from swizzled vbuf
#pragma unroll
    for (int kk = 0; kk < 2; ++kk) {
      bf16x8 pa = *(const bf16x8*)(plds_ + w * 1152 + l15 * STR + (kk << 5) + (lg << 3));
#pragma unroll
      for (int db = 0; db < 4; ++db) {
        const int d = (db << 4) + l15;
        const int c = (kk << 5) + (lg << 3);
        bf16x8 vb = *(const bf16x8*)(vbuf + d * 64 + (c ^ ((d & 7) << 3)));
        oacc[db] = mfma16(pa, vb, oacc[db]);
      }
    }
    // coop full-line store of this tile's normalized P (bf16 -> f32);
    // drains under next tile's staging + MFMA.
#pragma unroll
    for (int rr = 0; rr < 4; ++rr) {
      const int row = (rr << 4) + frow;
      bf16x4 pv4 = *(const bf16x4*)(plds_ + rr * 1152 + (row & 15) * STR + fcol);
      f32x4 o = { (float)pv4[0], (float)pv4[1], (float)pv4[2], (float)pv4[3] };
      __builtin_nontemporal_store(o,
          (f32x4*)(attn_bh + (size_t)(q0 + row) * S_ + (kt << 6) + fcol));
    }
  }

  // ctx write (P already normalized)
  const int b = bh >> 4, h = bh & 15;
  const int qr_base = q0 + (w << 4) + (lg << 2);
#pragma unroll
  for (int db = 0; db < 4; ++db) {
    const int d = (db << 4) + l15;
#pragma unroll
    for (int r = 0; r < 4; ++r) {
      const int qr = qr_base + r;
      ctx[((size_t)(b * S_ + qr)) * E_ + h * D_ + d] = (bf16_t)oacc[db][r];
    }
  }

  // zero-fill columns beyond the diagonal tile: full-line pattern
  const f32x4 fz = { 0.f, 0.f, 0.f, 0.f };
  for (int cb = q0 + 64; cb < S_; cb += 64) {
#pragma unroll
    for (int rr = 0; rr < 4; ++rr) {
      __builtin_nontemporal_store(fz,
          (f32x4*)(attn_bh + (size_t)(q0 + (rr << 4) + frow) * S_ + cb + fcol));
    }
  }
}

// ---------------------------------------------------------------------------
// Kernel 3: output projection, m97 structure.
// ---------------------------------------------------------------------------
__global__ __launch_bounds__(256) void out_gemm_kernel(
    bf16_t* __restrict__ wsb, const float* __restrict__ bo, float* __restrict__ out)
{
  __shared__ __align__(16) bf16_t sA[128 * 64];
  __shared__ __align__(16) bf16_t sB[128 * 64];

  const bf16_t* A  = wsb + OFF_CTX;
  const bf16_t* Bm = wsb + OFF_WB + 3u * WSZ;

  const int t = threadIdx.x, lane = t & 63, w = t >> 6;
  const int wm = (w >> 1) << 6, wn = (w & 1) << 6;
  const int m0 = blockIdx.x << 7, n0 = blockIdx.y << 7;
  const int l15 = lane & 15, lg = lane >> 4;

  const int r0 = w << 5;
  const int grow = r0 + (lane >> 3);
  const int gcol = (lane & 7) << 3;
  const bf16_t* gA = A + ((size_t)(m0 + grow) << 10) + gcol;
  const bf16_t* gB = Bm + ((size_t)(n0 + grow) << 10) + gcol;
  bf16_t* lA = sA + (r0 << 6);
  bf16_t* lB = sB + (r0 << 6);

  f32x4 acc[4][4] = {};

  for (int k0 = 0; k0 < E_; k0 += 64) {
    __syncthreads();
#pragma unroll
    for (int i = 0; i < 4; ++i) {
      gl_lds16(gA + k0 + ((size_t)(i << 3) << 10), lA + (i << 9));
      gl_lds16(gB + k0 + ((size_t)(i << 3) << 10), lB + (i << 9));
    }
    __syncthreads();
#pragma unroll
    for (int kk = 0; kk < 2; ++kk) {
      bf16x8 af[4], bfr[4];
#pragma unroll
      for (int i = 0; i < 4; ++i)
        af[i] = *(const bf16x8*)(sA + ((wm + (i << 4) + l15) << 6) + (kk << 5) + (lg << 3));
#pragma unroll
      for (int j = 0; j < 4; ++j)
        bfr[j] = *(const bf16x8*)(sB + ((wn + (j << 4) + l15) << 6) + (kk << 5) + (lg << 3));
#pragma unroll
      for (int i = 0; i < 4; ++i)
#pragma unroll
        for (int j = 0; j < 4; ++j)
          acc[i][j] = mfma16(af[i], bfr[j], acc[i][j]);
    }
  }

#pragma unroll
  for (int j = 0; j < 4; ++j) {
    const int n = n0 + wn + (j << 4) + l15;
    const float bn = bo[n];
#pragma unroll
    for (int i = 0; i < 4; ++i) {
#pragma unroll
      for (int r = 0; r < 4; ++r) {
        const int m = m0 + wm + (i << 4) + (lg << 2) + r;
        out[(size_t)m * E_ + n] = acc[i][j][r] + bn;
      }
    }
  }
}

// ---------------------------------------------------------------------------
extern "C" void kernel_launch(void* const* d_in, const int* in_sizes, int n_in,
                              void* d_out, int out_size, void* d_ws, size_t ws_size,
                              hipStream_t stream) {
  const float* query = (const float*)d_in[0];
  const float* key   = (const float*)d_in[1];
  const float* value = (const float*)d_in[2];
  const float* Wq = (const float*)d_in[4];
  const float* bq = (const float*)d_in[5];
  const float* Wk = (const float*)d_in[6];
  const float* bk = (const float*)d_in[7];
  const float* Wv = (const float*)d_in[8];
  const float* bv = (const float*)d_in[9];
  const float* Wo = (const float*)d_in[10];
  const float* bo = (const float*)d_in[11];

  float* out  = (float*)d_out;                       // [B,S,E]
  float* attn = out + (size_t)B_ * S_ * E_;          // [B,H,S,S]

  bf16_t* wsb = (bf16_t*)d_ws;
  bf16_t* qh  = wsb + OFF_QH;
  bf16_t* kh  = qh + XSZ;
  bf16_t* vh  = kh + XSZ;
  bf16_t* ctx = wsb + OFF_CTX;

  convert_kernel<<<dim3(512, 1, 7), dim3(256), 0, stream>>>(
      query, key, value, Wq, Wk, Wv, Wo, wsb);
  qkv_gemm_kernel<<<dim3(32, 8, 3), dim3(256), 0, stream>>>(wsb, bq, bk, bv);
  attn_kernel<<<dim3(1024), dim3(256), 0, stream>>>(qh, kh, vh, attn, ctx);
  out_gemm_kernel<<<dim3(32, 8), dim3(256), 0, stream>>>(wsb, bo, out);
}

// Round 18
// 215.052 us; speedup vs baseline: 1.1347x; 1.1347x over previous
//
#include <hip/hip_runtime.h>

#define B_ 2
#define S_ 2048
#define E_ 1024
#define H_ 16
#define D_ 64

typedef __bf16 bf16_t;
typedef __bf16 bf16x8 __attribute__((ext_vector_type(8)));
typedef __bf16 bf16x4 __attribute__((ext_vector_type(4)));
typedef float f32x4 __attribute__((ext_vector_type(4)));

// ws layout (bf16 element offsets)
#define OFF_XB   0u
#define OFF_WB   12582912u
#define OFF_QH   16777216u
#define OFF_CTX  29360128u
#define XSZ      4194304u
#define WSZ      1048576u

__device__ __forceinline__ f32x4 mfma16(bf16x8 a, bf16x8 b, f32x4 c) {
  return __builtin_amdgcn_mfma_f32_16x16x32_bf16(a, b, c, 0, 0, 0);
}

__device__ __forceinline__ void gl_lds16(const bf16_t* g, bf16_t* l) {
  __builtin_amdgcn_global_load_lds(
      (const __attribute__((address_space(1))) void*)g,
      (__attribute__((address_space(3))) void*)l, 16, 0, 0);
}

// ---------------------------------------------------------------------------
// Kernel 0: fp32 -> bf16 convert into ws.
// ---------------------------------------------------------------------------
__global__ __launch_bounds__(256) void convert_kernel(
    const float* __restrict__ q, const float* __restrict__ k, const float* __restrict__ v,
    const float* __restrict__ wq, const float* __restrict__ wk,
    const float* __restrict__ wv, const float* __restrict__ wo,
    bf16_t* __restrict__ ws)
{
  const int z = blockIdx.z;
  const float* src;
  bf16_t* dst;
  int n;
  if (z < 3) {
    src = (z == 0) ? q : (z == 1) ? k : v;
    dst = ws + (size_t)z * XSZ;
    n = XSZ;
  } else {
    src = (z == 3) ? wq : (z == 4) ? wk : (z == 5) ? wv : wo;
    dst = ws + OFF_WB + (size_t)(z - 3) * WSZ;
    n = WSZ;
  }
  const int stride = 512 * 256 * 8;
  for (int base = (int)(blockIdx.x * 256 + threadIdx.x) * 8; base < n; base += stride) {
    float4 a = *(const float4*)(src + base);
    float4 b = *(const float4*)(src + base + 4);
    bf16x8 o = { (bf16_t)a.x, (bf16_t)a.y, (bf16_t)a.z, (bf16_t)a.w,
                 (bf16_t)b.x, (bf16_t)b.y, (bf16_t)b.z, (bf16_t)b.w };
    *(bf16x8*)(dst + base) = o;
  }
}

// ---------------------------------------------------------------------------
// Kernel 1: QKV projection, m97 structure.
// ---------------------------------------------------------------------------
__global__ __launch_bounds__(256) void qkv_gemm_kernel(
    bf16_t* __restrict__ wsb,
    const float* __restrict__ bq, const float* __restrict__ bk, const float* __restrict__ bv)
{
  __shared__ __align__(16) bf16_t sA[128 * 64];
  __shared__ __align__(16) bf16_t sB[128 * 64];

  const int z = blockIdx.z;
  const bf16_t* A  = wsb + (size_t)z * XSZ;
  const bf16_t* Bm = wsb + OFF_WB + (size_t)z * WSZ;
  const float* bias = (z == 0) ? bq : (z == 1) ? bk : bv;
  bf16_t* out = wsb + OFF_QH + (size_t)z * XSZ;

  const int t = threadIdx.x, lane = t & 63, w = t >> 6;
  const int wm = (w >> 1) << 6, wn = (w & 1) << 6;
  const int m0 = blockIdx.x << 7, n0 = blockIdx.y << 7;
  const int l15 = lane & 15, lg = lane >> 4;

  const int r0 = w << 5;
  const int grow = r0 + (lane >> 3);
  const int gcol = (lane & 7) << 3;
  const bf16_t* gA = A + ((size_t)(m0 + grow) << 10) + gcol;
  const bf16_t* gB = Bm + ((size_t)(n0 + grow) << 10) + gcol;
  bf16_t* lA = sA + (r0 << 6);
  bf16_t* lB = sB + (r0 << 6);

  f32x4 acc[4][4] = {};

  for (int k0 = 0; k0 < E_; k0 += 64) {
    __syncthreads();
#pragma unroll
    for (int i = 0; i < 4; ++i) {
      gl_lds16(gA + k0 + ((size_t)(i << 3) << 10), lA + (i << 9));
      gl_lds16(gB + k0 + ((size_t)(i << 3) << 10), lB + (i << 9));
    }
    __syncthreads();
#pragma unroll
    for (int kk = 0; kk < 2; ++kk) {
      bf16x8 af[4], bfr[4];
#pragma unroll
      for (int i = 0; i < 4; ++i)
        af[i] = *(const bf16x8*)(sA + ((wm + (i << 4) + l15) << 6) + (kk << 5) + (lg << 3));
#pragma unroll
      for (int j = 0; j < 4; ++j)
        bfr[j] = *(const bf16x8*)(sB + ((wn + (j << 4) + l15) << 6) + (kk << 5) + (lg << 3));
#pragma unroll
      for (int i = 0; i < 4; ++i)
#pragma unroll
        for (int j = 0; j < 4; ++j)
          acc[i][j] = mfma16(af[i], bfr[j], acc[i][j]);
    }
  }

#pragma unroll
  for (int j = 0; j < 4; ++j) {
    const int n = n0 + wn + (j << 4) + l15;
    const float bn = bias[n];
    const int h = n >> 6, d = n & 63;
#pragma unroll
    for (int i = 0; i < 4; ++i) {
#pragma unroll
      for (int r = 0; r < 4; ++r) {
        const int m = m0 + wm + (i << 4) + (lg << 2) + r;
        const int b = m >> 11, s = m & (S_ - 1);
        out[(((size_t)(b * H_ + h)) * S_ + s) * D_ + d] = (bf16_t)(acc[i][j][r] + bn);
      }
    }
  }
}

// ---------------------------------------------------------------------------
// Kernel 2: fused causal attention (R14 structure) with global_load_lds
// staging.  K: linear [64][64] LDS, content XOR-swizzled via PRE-SWIZZLED
// global source (rule #21: swizzle both sides); reads apply the same XOR
// (conflict level unchanged vs padded layout, staging ds_writes eliminated).
// V: linear [64][64], gl_lds direct; in-place swizzled V^T as in R14.
// ---------------------------------------------------------------------------
__global__ __launch_bounds__(256, 6) void attn_kernel(
    const bf16_t* __restrict__ qh, const bf16_t* __restrict__ kh, const bf16_t* __restrict__ vh,
    float* __restrict__ attn, bf16_t* __restrict__ ctx)
{
  constexpr int STR = 72;                        // plds row stride only
  __shared__ __align__(16) char smem[25600];
  bf16_t* klds  = (bf16_t*)smem;                 // [64][64] linear, swz content
  bf16_t* vbuf  = (bf16_t*)(smem + 8192);        // [64][64] V rows -> V^T swz
  bf16_t* plds_ = (bf16_t*)(smem + 16384);       // 4 x [16][72]
  float*  pf    = (float*)(smem + 8192);         // [64][68] f32 = 17408 B

  // --- XCD-aware remap: XCD(d)=d%8 owns bh in {4*xcd .. 4*xcd+3} ---
  const int d_  = blockIdx.x;          // 0..1023
  const int xcd = d_ & 7;
  const int bh  = (xcd << 2) + ((d_ >> 3) & 3);
  const int qt  = d_ >> 5;             // 0..31

  const int t    = threadIdx.x;
  const int lane = t & 63;
  const int w    = t >> 6;
  const int l15  = lane & 15;
  const int lg   = lane >> 4;
  const int q0 = qt << 6;
  const size_t hbase = (size_t)bh * (size_t)(S_ * D_);

  const int qr_lane = q0 + (w << 4) + l15;
  const bf16_t* qp = qh + hbase + (size_t)qr_lane * D_ + (lg << 3);
  const bf16x8 q_lo = *(const bf16x8*)qp;
  const bf16x8 q_hi = *(const bf16x8*)(qp + 32);

  constexpr float SC = 0.18033688f;  // log2(e)/8

  float s_sum = 0.f;
  f32x4 oacc[4] = {};

  const int td  = t & 63;
  const int tk0 = (t >> 6) << 3;     // 0,8,16,24 (col octet per wave)
  // in-place V^T (swizzled) write addresses
  const int vtw0 = td * 64 + (tk0 ^ ((td & 7) << 3));
  const int vtw1 = td * 64 + ((tk0 + 32) ^ ((td & 7) << 3));

  // gl_lds staging geometry: wave w, inst i covers rows w*16+i*8 .. +7
  // (1KB per wave-inst, lane l -> row +(l>>3), 16B granule g=l&7)
  const int rw0 = (w << 4) + (lane >> 3);
  const int rw1 = rw0 + 8;
  const int g   = lane & 7;
  const int kswz = ((g ^ (lane >> 3)) << 3);     // rw0&7 == rw1&7 == lane>>3
  bf16_t* kdst0 = klds + ((w << 1) << 9);
  bf16_t* kdst1 = klds + (((w << 1) + 1) << 9);
  bf16_t* vdst0 = vbuf + ((w << 1) << 9);
  bf16_t* vdst1 = vbuf + (((w << 1) + 1) << 9);

  // swizzled K fragment read offsets (row = j*16 + l15; r7 = l15&7)
  const int r7 = l15 & 7;
  const int koff_lo = ((lg ^ r7) << 3);
  const int koff_hi = (((lg + 4) ^ r7) << 3);

  // ---- pass A: sums + PV ----
  for (int kt = 0; kt <= qt; ++kt) {
    __syncthreads();   // prev tile PV/vbuf reads done
    {
      const bf16_t* kb = kh + hbase + ((size_t)(kt << 6) << 6);
      const bf16_t* vb = vh + hbase + ((size_t)(kt << 6) << 6);
      gl_lds16(kb + (rw0 << 6) + kswz, kdst0);
      gl_lds16(kb + (rw1 << 6) + kswz, kdst1);
      gl_lds16(vb + (rw0 << 6) + (g << 3), vdst0);
      gl_lds16(vb + (rw1 << 6) + (g << 3), vdst1);
    }
    __syncthreads();   // staging visible (drains vmcnt)
    // transpose-read V columns into registers
    bf16x8 col0, col1;
#pragma unroll
    for (int e = 0; e < 8; ++e) col0[e] = vbuf[((tk0 + e) << 6) + td];
#pragma unroll
    for (int e = 0; e < 8; ++e) col1[e] = vbuf[((tk0 + 32 + e) << 6) + td];
    // swapped QK^T: per j, lane holds P[qr_lane][kc..kc+3]
#pragma unroll
    for (int j = 0; j < 4; ++j) {
      const bf16_t* kp = klds + (((j << 4) + l15) << 6);
      bf16x8 k_lo = *(const bf16x8*)(kp + koff_lo);
      bf16x8 k_hi = *(const bf16x8*)(kp + koff_hi);
      f32x4 sf = { 0.f, 0.f, 0.f, 0.f };
      sf = mfma16(k_lo, q_lo, sf);
      sf = mfma16(k_hi, q_hi, sf);
      const int kc = (kt << 6) + (j << 4) + (lg << 2);
      const int lim = qr_lane - kc;
      bf16x4 pb;
#pragma unroll
      for (int r = 0; r < 4; ++r) {
        const float pv = (r <= lim) ? exp2f(sf[r] * SC) : 0.f;
        s_sum += pv;
        pb[r] = (bf16_t)pv;
      }
      *(bf16x4*)(plds_ + w * 1152 + l15 * STR + (j << 4) + (lg << 2)) = pb;
    }
    __syncthreads();   // all transpose-reads complete
    // write V^T (swizzled) back into vbuf
    *(bf16x8*)(vbuf + vtw0) = col0;
    *(bf16x8*)(vbuf + vtw1) = col1;
    __syncthreads();   // V^T visible
    // PV: pa from plds (wave-private), vb from swizzled vbuf
#pragma unroll
    for (int kk = 0; kk < 2; ++kk) {
      bf16x8 pa = *(const bf16x8*)(plds_ + w * 1152 + l15 * STR + (kk << 5) + (lg << 3));
#pragma unroll
      for (int db = 0; db < 4; ++db) {
        const int d = (db << 4) + l15;
        const int c = (kk << 5) + (lg << 3);
        bf16x8 vb = *(const bf16x8*)(vbuf + d * 64 + (c ^ ((d & 7) << 3)));
        oacc[db] = mfma16(pa, vb, oacc[db]);
      }
    }
  }

  float s = s_sum;
  s += __shfl_xor(s, 16);
  s += __shfl_xor(s, 32);
  const float inv_s = 1.f / s;

  float rinv[4];
#pragma unroll
  for (int r = 0; r < 4; ++r) rinv[r] = __shfl(inv_s, (lg << 2) + r);

  const int b = bh >> 4, h = bh & 15;
  const int qr_base = q0 + (w << 4) + (lg << 2);
#pragma unroll
  for (int db = 0; db < 4; ++db) {
    const int d = (db << 4) + l15;
#pragma unroll
    for (int r = 0; r < 4; ++r) {
      const int qr = qr_base + r;
      ctx[((size_t)(b * S_ + qr)) * E_ + h * D_ + d] = (bf16_t)(oacc[db][r] * rinv[r]);
    }
  }

  // ---- pass B: recompute scores -> LDS f32 tile -> full-line nt stores ----
  float* attn_bh = attn + (size_t)bh * (size_t)(S_ * S_);
  const int frow = t >> 4;
  const int fcol = (t & 15) << 2;
  for (int kt = 0; kt <= qt; ++kt) {
    __syncthreads();   // prev coop-store LDS reads done
    {
      const bf16_t* kb = kh + hbase + ((size_t)(kt << 6) << 6);
      gl_lds16(kb + (rw0 << 6) + kswz, kdst0);
      gl_lds16(kb + (rw1 << 6) + kswz, kdst1);
    }
    __syncthreads();
#pragma unroll
    for (int j = 0; j < 4; ++j) {
      const bf16_t* kp = klds + (((j << 4) + l15) << 6);
      bf16x8 k_lo = *(const bf16x8*)(kp + koff_lo);
      bf16x8 k_hi = *(const bf16x8*)(kp + koff_hi);
      f32x4 sf = { 0.f, 0.f, 0.f, 0.f };
      sf = mfma16(k_lo, q_lo, sf);
      sf = mfma16(k_hi, q_hi, sf);
      const int kc = (kt << 6) + (j << 4) + (lg << 2);
      const int lim = qr_lane - kc;
      f32x4 o;
#pragma unroll
      for (int r = 0; r < 4; ++r)
        o[r] = (r <= lim) ? exp2f(sf[r] * SC) * inv_s : 0.f;
      *(f32x4*)(pf + ((w << 4) + l15) * 68 + (j << 4) + (lg << 2)) = o;
    }
    __syncthreads();   // pf complete across all waves
    // cooperative store: 16 lanes x 16B = 256B contiguous per row
#pragma unroll
    for (int rr = 0; rr < 4; ++rr) {
      const int row = (rr << 4) + frow;
      f32x4 v = *(const f32x4*)(pf + row * 68 + fcol);
      __builtin_nontemporal_store(v,
          (f32x4*)(attn_bh + (size_t)(q0 + row) * S_ + (kt << 6) + fcol));
    }
  }

  // zero-fill columns beyond the diagonal tile: full-line pattern
  const f32x4 fz = { 0.f, 0.f, 0.f, 0.f };
  for (int cb = q0 + 64; cb < S_; cb += 64) {
#pragma unroll
    for (int rr = 0; rr < 4; ++rr) {
      __builtin_nontemporal_store(fz,
          (f32x4*)(attn_bh + (size_t)(q0 + (rr << 4) + frow) * S_ + cb + fcol));
    }
  }
}

// ---------------------------------------------------------------------------
// Kernel 3: output projection, m97 structure.
// ---------------------------------------------------------------------------
__global__ __launch_bounds__(256) void out_gemm_kernel(
    bf16_t* __restrict__ wsb, const float* __restrict__ bo, float* __restrict__ out)
{
  __shared__ __align__(16) bf16_t sA[128 * 64];
  __shared__ __align__(16) bf16_t sB[128 * 64];

  const bf16_t* A  = wsb + OFF_CTX;
  const bf16_t* Bm = wsb + OFF_WB + 3u * WSZ;

  const int t = threadIdx.x, lane = t & 63, w = t >> 6;
  const int wm = (w >> 1) << 6, wn = (w & 1) << 6;
  const int m0 = blockIdx.x << 7, n0 = blockIdx.y << 7;
  const int l15 = lane & 15, lg = lane >> 4;

  const int r0 = w << 5;
  const int grow = r0 + (lane >> 3);
  const int gcol = (lane & 7) << 3;
  const bf16_t* gA = A + ((size_t)(m0 + grow) << 10) + gcol;
  const bf16_t* gB = Bm + ((size_t)(n0 + grow) << 10) + gcol;
  bf16_t* lA = sA + (r0 << 6);
  bf16_t* lB = sB + (r0 << 6);

  f32x4 acc[4][4] = {};

  for (int k0 = 0; k0 < E_; k0 += 64) {
    __syncthreads();
#pragma unroll
    for (int i = 0; i < 4; ++i) {
      gl_lds16(gA + k0 + ((size_t)(i << 3) << 10), lA + (i << 9));
      gl_lds16(gB + k0 + ((size_t)(i << 3) << 10), lB + (i << 9));
    }
    __syncthreads();
#pragma unroll
    for (int kk = 0; kk < 2; ++kk) {
      bf16x8 af[4], bfr[4];
#pragma unroll
      for (int i = 0; i < 4; ++i)
        af[i] = *(const bf16x8*)(sA + ((wm + (i << 4) + l15) << 6) + (kk << 5) + (lg << 3));
#pragma unroll
      for (int j = 0; j < 4; ++j)
        bfr[j] = *(const bf16x8*)(sB + ((wn + (j << 4) + l15) << 6) + (kk << 5) + (lg << 3));
#pragma unroll
      for (int i = 0; i < 4; ++i)
#pragma unroll
        for (int j = 0; j < 4; ++j)
          acc[i][j] = mfma16(af[i], bfr[j], acc[i][j]);
    }
  }

#pragma unroll
  for (int j = 0; j < 4; ++j) {
    const int n = n0 + wn + (j << 4) + l15;
    const float bn = bo[n];
#pragma unroll
    for (int i = 0; i < 4; ++i) {
#pragma unroll
      for (int r = 0; r < 4; ++r) {
        const int m = m0 + wm + (i << 4) + (lg << 2) + r;
        out[(size_t)m * E_ + n] = acc[i][j][r] + bn;
      }
    }
  }
}

// ---------------------------------------------------------------------------
extern "C" void kernel_launch(void* const* d_in, const int* in_sizes, int n_in,
                              void* d_out, int out_size, void* d_ws, size_t ws_size,
                              hipStream_t stream) {
  const float* query = (const float*)d_in[0];
  const float* key   = (const float*)d_in[1];
  const float* value = (const float*)d_in[2];
  const float* Wq = (const float*)d_in[4];
  const float* bq = (const float*)d_in[5];
  const float* Wk = (const float*)d_in[6];
  const float* bk = (const float*)d_in[7];
  const float* Wv = (const float*)d_in[8];
  const float* bv = (const float*)d_in[9];
  const float* Wo = (const float*)d_in[10];
  const float* bo = (const float*)d_in[11];

  float* out  = (float*)d_out;                       // [B,S,E]
  float* attn = out + (size_t)B_ * S_ * E_;          // [B,H,S,S]

  bf16_t* wsb = (bf16_t*)d_ws;
  bf16_t* qh  = wsb + OFF_QH;
  bf16_t* kh  = qh + XSZ;
  bf16_t* vh  = kh + XSZ;
  bf16_t* ctx = wsb + OFF_CTX;

  convert_kernel<<<dim3(512, 1, 7), dim3(256), 0, stream>>>(
      query, key, value, Wq, Wk, Wv, Wo, wsb);
  qkv_gemm_kernel<<<dim3(32, 8, 3), dim3(256), 0, stream>>>(wsb, bq, bk, bv);
  attn_kernel<<<dim3(1024), dim3(256), 0, stream>>>(qh, kh, vh, attn, ctx);
  out_gemm_kernel<<<dim3(32, 8), dim3(256), 0, stream>>>(wsb, bo, out);
}